// Round 4
// baseline (917.111 us; speedup 1.0000x reference)
//
#include <hip/hip_runtime.h>
#include <hip/hip_bf16.h>

#define NN 10000
#define EE 160000
#define CCH 4
#define CF 16
#define RR 7
#define HH 256
#define EPSV 1e-5f

typedef unsigned short ushort_t;
typedef __bf16 bf16x8 __attribute__((ext_vector_type(8)));
typedef float f32x4 __attribute__((ext_vector_type(4)));

// fast silu: v * rcp(1 + exp2(-v*log2e)); bf16-accurate, avoids full-rate divide
__device__ __forceinline__ float silu_f(float v) {
    float e = __builtin_amdgcn_exp2f(v * -1.442695040888963f);
    return v * __builtin_amdgcn_rcpf(1.f + e);
}

__device__ __forceinline__ ushort_t bf16u(float f) {
    unsigned int u = __builtin_bit_cast(unsigned int, f);
    u += 0x7fffu + ((u >> 16) & 1u);
    return (ushort_t)(u >> 16);
}

__device__ __forceinline__ float ubf2f(ushort_t u) {
    unsigned int v = ((unsigned int)u) << 16;
    return __builtin_bit_cast(float, v);
}

// ---------------- prep kernels ----------------

__global__ __launch_bounds__(256) void ca_kernel(
    const float* __restrict__ attr, const float* __restrict__ cw,
    float* __restrict__ ca)
{
    int t = blockIdx.x * 256 + threadIdx.x;
    if (t < NN * CF) {
        int n = t >> 4, f = t & 15;
        float s = 0.f, cs = 0.f;
        #pragma unroll
        for (int c = 0; c < CCH; ++c) {
            float w = cw[n * CCH + c];
            s  += attr[(n * CCH + c) * CF + f] * w;
            cs += w;
        }
        ca[t] = s / cs;
    }
}

__global__ __launch_bounds__(256) void deg_kernel(
    const int* __restrict__ el, float* __restrict__ deg)
{
    int e = blockIdx.x * 256 + threadIdx.x;
    if (e < EE) atomicAdd(&deg[el[e * 3]], 1.f);
}

__global__ __launch_bounds__(256) void cvt_kernel(
    const float* __restrict__ s, ushort_t* __restrict__ d, int n)
{
    int t = blockIdx.x * 256 + threadIdx.x;
    if (t < n) d[t] = bf16u(s[t]);
}

// Pack W (Kreal x N row-major fp32) into MFMA B-fragment order, bf16.
__global__ __launch_bounds__(64) void pack_kernel(
    const float* __restrict__ W, ushort_t* __restrict__ out,
    int Kreal, int N)
{
    int kt = blockIdx.x, nt = blockIdx.y, NTOT = gridDim.y;
    int lane = threadIdx.x;
    int n = nt * 16 + (lane & 15);
    int kbase = kt * 32 + (lane >> 4) * 8;
    ushort_t* o = out + ((size_t)(kt * NTOT + nt) * 64 + lane) * 8;
    #pragma unroll
    for (int j = 0; j < 8; ++j) {
        int k = kbase + j;
        o[j] = (k < Kreal) ? bf16u(W[(size_t)k * N + n]) : (ushort_t)0;
    }
}

// ---------------- MFMA stage helper (16-edge M-tile) ----------------
// A in LDS (16 rows, stride 584 bf16). Wave w covers cols [w*64, w*64+64).

template<int KT, int NTOT>
__device__ __forceinline__ void mfma_stage16(
    const ushort_t (&A)[16][584], int colOff,
    const ushort_t* __restrict__ Wp, int w, int lane,
    f32x4 (&acc)[4])
{
    const f32x4 Z = {0.f, 0.f, 0.f, 0.f};
    #pragma unroll
    for (int j = 0; j < 4; ++j) acc[j] = Z;
    const int ar = lane & 15, aq = (lane >> 4) * 8;
    for (int kt = 0; kt < KT; ++kt) {
        bf16x8 a = *(const bf16x8*)&A[ar][colOff + kt * 32 + aq];
        #pragma unroll
        for (int j = 0; j < 4; ++j) {
            bf16x8 b = *(const bf16x8*)(Wp + ((size_t)(kt * NTOT + w * 4 + j) * 64 + lane) * 8);
            acc[j] = __builtin_amdgcn_mfma_f32_16x16x32_bf16(a, b, acc[j], 0, 0, 0);
        }
    }
}

// ---------------- fused edge kernel (16 edges/block, 8 blk/CU) ----------------

__global__ __launch_bounds__(256, 8) void edge_kernel(
    const int* __restrict__ el, const float* __restrict__ cw,
    const float* __restrict__ ew, const float* __restrict__ x,
    const ushort_t* __restrict__ hb16, const ushort_t* __restrict__ cab16,
    const float* __restrict__ W_rad, const float* __restrict__ b_rad,
    const ushort_t* __restrict__ pe1, const float* __restrict__ b_e1,
    const ushort_t* __restrict__ pe2, const float* __restrict__ b_e2,
    const ushort_t* __restrict__ pc1, const float* __restrict__ b_c1,
    const ushort_t* __restrict__ pc2,
    float* __restrict__ agg, float* __restrict__ xacc)
{
    // Region map per row: X = cols 0..255, Y = cols 288..543.
    // e1 reads 0..575 -> t1 in Y -> e2 reads Y, m -> X -> c1 reads X,
    // t2 -> Y -> c2 reads Y. m (X) survives to kernel end for agg atomics.
    __shared__ ushort_t abuf[16][584];   // 18688 B
    __shared__ float radbuf[16][16];     // radial, later phi
    __shared__ int rowS[16], colS[16], relS[16];
    __shared__ float ewS[16];

    const int tid = threadIdx.x, lane = tid & 63, w = tid >> 6;
    const int ar = lane & 15, aq = (lane >> 4) * 8, quad = lane >> 4;
    const int e0 = blockIdx.x * 16;

    if (tid < 16) {
        rowS[tid] = el[(e0 + tid) * 3 + 0];
        colS[tid] = el[(e0 + tid) * 3 + 1];
        relS[tid] = el[(e0 + tid) * 3 + 2];
        ewS[tid]  = ew[e0 + tid];
    }
    __syncthreads();   // B1

    // ---- staging: h (1024 x16B chunks), ca (64), pad (32), radial (256) ----
    #pragma unroll
    for (int it = 0; it < 4; ++it) {
        int c = it * 256 + tid;
        int e = c >> 6, half = (c >> 5) & 1, idx = c & 31;
        int node = half ? colS[e] : rowS[e];
        *(uint4*)&abuf[e][half * 256 + idx * 8] =
            ((const uint4*)(hb16 + (size_t)node * 256))[idx];
    }
    if (tid < 64) {
        int e = tid >> 2, half2 = (tid >> 1) & 1, idx = tid & 1;
        int node = half2 ? colS[e] : rowS[e];
        *(uint4*)&abuf[e][528 + half2 * 16 + idx * 8] =
            ((const uint4*)(cab16 + node * 16))[idx];
    } else if (tid < 96) {
        int c = tid - 64, e = c >> 1, idx = c & 1;
        uint4 z = {0u, 0u, 0u, 0u};
        *(uint4*)&abuf[e][560 + idx * 8] = z;
    }
    {
        int e = tid >> 4, ab = tid & 15, a = ab >> 2, b = ab & 3;
        int row = rowS[e], col = colS[e];
        float d0 = x[row * 12 + a * 3 + 0] - x[col * 12 + b * 3 + 0];
        float d1 = x[row * 12 + a * 3 + 1] - x[col * 12 + b * 3 + 1];
        float d2 = x[row * 12 + a * 3 + 2] - x[col * 12 + b * 3 + 2];
        radbuf[e][ab] = (d0 * d0 + d1 * d1 + d2 * d2)
                      * cw[row * CCH + a] * cw[col * CCH + b];
    }
    __syncthreads();   // B2

    // rad_feat -> abuf cols 512..527
    {
        int e = tid >> 4, f = tid & 15;
        float acc = b_rad[f];
        #pragma unroll
        for (int ab = 0; ab < 16; ++ab) acc += radbuf[e][ab] * W_rad[ab * 16 + f];
        abuf[e][512 + f] = bf16u(silu_f(acc));
    }
    __syncthreads();   // B3

    f32x4 acc[4];

    // ---- e1: reads cols 0..575 ----
    mfma_stage16<18, 16>(abuf, 0, pe1, w, lane, acc);
    __syncthreads();   // B4 (epilogue writes Y which overlaps e1 input)
    #pragma unroll
    for (int j = 0; j < 4; ++j) {
        int n = w * 64 + j * 16 + ar;
        float bj = b_e1[n];
        #pragma unroll
        for (int r = 0; r < 4; ++r)
            abuf[quad * 4 + r][288 + n] = bf16u(silu_f(acc[j][r] + bj));
    }
    __syncthreads();   // B5

    // ---- e2: reads Y, writes m -> X (disjoint) ----
    mfma_stage16<8, 16>(abuf, 288, pe2, w, lane, acc);
    #pragma unroll
    for (int j = 0; j < 4; ++j) {
        int n = w * 64 + j * 16 + ar;
        float bj = b_e2[n];
        #pragma unroll
        for (int r = 0; r < 4; ++r) {
            int e = quad * 4 + r;
            abuf[e][n] = bf16u(silu_f(acc[j][r] + bj) * ewS[e]);
        }
    }
    __syncthreads();   // B6

    // ---- c1: reads X, writes t2 -> Y ----
    mfma_stage16<8, 16>(abuf, 0, pc1, w, lane, acc);
    #pragma unroll
    for (int j = 0; j < 4; ++j) {
        int n = w * 64 + j * 16 + ar;
        float bj = b_c1[n];
        #pragma unroll
        for (int r = 0; r < 4; ++r)
            abuf[quad * 4 + r][288 + n] = bf16u(silu_f(acc[j][r] + bj));
    }
    __syncthreads();   // B7

    // ---- c2: wave 0 computes phi for all 16 edges -> radbuf ----
    if (w == 0) {
        const f32x4 Z = {0.f, 0.f, 0.f, 0.f};
        f32x4 p = Z;
        #pragma unroll
        for (int kt = 0; kt < 8; ++kt) {
            bf16x8 a = *(const bf16x8*)&abuf[ar][288 + kt * 32 + aq];
            bf16x8 b = *(const bf16x8*)(pc2 + ((size_t)kt * 64 + lane) * 8);
            p = __builtin_amdgcn_mfma_f32_16x16x32_bf16(a, b, p, 0, 0, 0);
        }
        #pragma unroll
        for (int r = 0; r < 4; ++r)
            radbuf[quad * 4 + r][ar] = p[r];
    }
    __syncthreads();   // B8

    // ---- trans -> xacc (xd recomputed from L1-hot x) ----
    if (tid < 192) {
        int e = tid / 12, r = tid - e * 12, a = r / 3, k = r - a * 3;
        int row = rowS[e], col = colS[e];
        float xr = x[row * 12 + a * 3 + k];
        float s = 0.f;
        #pragma unroll
        for (int b = 0; b < 4; ++b)
            s += (xr - x[col * 12 + b * 3 + k]) * radbuf[e][a * 4 + b];
        atomicAdd(&xacc[row * 12 + a * 3 + k], 0.25f * s);
    }

    // ---- deferred agg atomics: re-read m from X; no barrier drains these ----
    #pragma unroll
    for (int j = 0; j < 4; ++j) {
        int n = w * 64 + j * 16 + ar;
        #pragma unroll
        for (int r = 0; r < 4; ++r) {
            int e = quad * 4 + r;
            float m = ubf2f(abuf[e][n]);
            atomicAdd(&agg[((size_t)colS[e] * RR + relS[e]) * HH + n], m);
        }
    }
}

// ---------------- fused node kernel (n1 + n2 + LN, 16 nodes/block) ----------------

__global__ __launch_bounds__(256, 3) void node_kernel(
    const float* __restrict__ agg, const float* __restrict__ hsrc,
    const ushort_t* __restrict__ pn1, const float* __restrict__ b_n1,
    const ushort_t* __restrict__ pn2, const float* __restrict__ b_n2,
    const float* __restrict__ ln_g, const float* __restrict__ ln_b,
    float* __restrict__ h_out, ushort_t* __restrict__ hb16o)
{
    __shared__ __align__(16) char arena[33024];
    __shared__ ushort_t tbuf[16][264];
    __shared__ float redS[16][16], red2S[16][16], muS[16], rsS[16];
    ushort_t (*nbuf)[1032] = (ushort_t(*)[1032])arena;
    float (*h2buf)[264] = (float(*)[264])arena;

    const int tid = threadIdx.x, lane = tid & 63, w = tid >> 6;
    const int n0 = blockIdx.x * 16;
    const int ar = lane & 15, aq = (lane >> 4) * 8;
    const f32x4 Z = {0.f, 0.f, 0.f, 0.f};

    f32x4 acc[4] = {Z, Z, Z, Z};
    for (int chunk = 0; chunk < 2; ++chunk) {
        for (int t = tid; t < 4096; t += 256) {
            int node = t >> 8, i4 = t & 255;
            int g4 = chunk * 256 + i4;
            float4 v;
            if (g4 < 448) v = ((const float4*)(agg + (size_t)(n0 + node) * 1792))[g4];
            else          v = ((const float4*)(hsrc + (size_t)(n0 + node) * 256))[g4 - 448];
            ushort4 u;
            u.x = bf16u(v.x); u.y = bf16u(v.y); u.z = bf16u(v.z); u.w = bf16u(v.w);
            *(ushort4*)&nbuf[node][i4 * 4] = u;
        }
        __syncthreads();
        for (int kt = 0; kt < 32; ++kt) {
            bf16x8 a = *(const bf16x8*)&nbuf[ar][kt * 32 + aq];
            int ktg = chunk * 32 + kt;
            #pragma unroll
            for (int j = 0; j < 4; ++j) {
                bf16x8 b = *(const bf16x8*)(pn1 + ((size_t)(ktg * 16 + w * 4 + j) * 64 + lane) * 8);
                acc[j] = __builtin_amdgcn_mfma_f32_16x16x32_bf16(a, b, acc[j], 0, 0, 0);
            }
        }
        __syncthreads();
    }
    #pragma unroll
    for (int j = 0; j < 4; ++j) {
        int n = w * 64 + j * 16 + ar;
        float bj = b_n1[n];
        #pragma unroll
        for (int r = 0; r < 4; ++r)
            tbuf[(lane >> 4) * 4 + r][n] = bf16u(silu_f(acc[j][r] + bj));
    }
    __syncthreads();
    f32x4 acc2[4] = {Z, Z, Z, Z};
    for (int kt = 0; kt < 8; ++kt) {
        bf16x8 a = *(const bf16x8*)&tbuf[ar][kt * 32 + aq];
        #pragma unroll
        for (int j = 0; j < 4; ++j) {
            bf16x8 b = *(const bf16x8*)(pn2 + ((size_t)(kt * 16 + w * 4 + j) * 64 + lane) * 8);
            acc2[j] = __builtin_amdgcn_mfma_f32_16x16x32_bf16(a, b, acc2[j], 0, 0, 0);
        }
    }
    float hv[4][4];
    #pragma unroll
    for (int j = 0; j < 4; ++j) {
        int n = w * 64 + j * 16 + ar;
        float bj = b_n2[n];
        #pragma unroll
        for (int r = 0; r < 4; ++r) {
            hv[j][r] = acc2[j][r] + bj;
            h2buf[(lane >> 4) * 4 + r][n] = hv[j][r];
        }
    }
    __syncthreads();
    {
        int node = tid >> 4, c = tid & 15;
        float s = 0.f, s2 = 0.f;
        #pragma unroll
        for (int i = 0; i < 16; ++i) {
            float v = h2buf[node][c * 16 + i];
            s += v; s2 += v * v;
        }
        redS[node][c] = s; red2S[node][c] = s2;
    }
    __syncthreads();
    if (tid < 16) {
        float s = 0.f, s2 = 0.f;
        #pragma unroll
        for (int c = 0; c < 16; ++c) { s += redS[tid][c]; s2 += red2S[tid][c]; }
        float mu = s * (1.f / 256.f);
        muS[tid] = mu;
        rsS[tid] = rsqrtf(s2 * (1.f / 256.f) - mu * mu + EPSV);
    }
    __syncthreads();
    #pragma unroll
    for (int j = 0; j < 4; ++j) {
        int n = w * 64 + j * 16 + ar;
        float g = ln_g[n], bb = ln_b[n];
        #pragma unroll
        for (int r = 0; r < 4; ++r) {
            int row = (lane >> 4) * 4 + r;
            float v = (hv[j][r] - muS[row]) * rsS[row] * g + bb;
            h_out[(size_t)(n0 + row) * HH + n] = v;
            hb16o[(size_t)(n0 + row) * HH + n] = bf16u(v);
        }
    }
}

__global__ __launch_bounds__(256) void xout_kernel(
    const float* __restrict__ x_in, const float* __restrict__ xacc,
    const float* __restrict__ deg, float* __restrict__ x_out)
{
    int t = blockIdx.x * 256 + threadIdx.x;
    if (t < NN * 12) {
        int n = t / 12;
        float c = fmaxf(deg[n], 1.f);
        x_out[t] = x_in[t] + xacc[t] / c;
    }
}

// ---------------- launcher ----------------

extern "C" void kernel_launch(void* const* d_in, const int* in_sizes, int n_in,
                              void* d_out, int out_size, void* d_ws, size_t ws_size,
                              hipStream_t stream)
{
    const float* input  = (const float*)d_in[0];
    const float* coords = (const float*)d_in[1];
    const float* cattr  = (const float*)d_in[2];
    const float* cwts   = (const float*)d_in[3];
    const float* ewts   = (const float*)d_in[4];
    const int*   elist  = (const int*)d_in[5];
    const float* W_rad  = (const float*)d_in[6];
    const float* b_rad  = (const float*)d_in[7];
    const float* W_e1   = (const float*)d_in[8];
    const float* b_e1   = (const float*)d_in[9];
    const float* W_e2   = (const float*)d_in[10];
    const float* b_e2   = (const float*)d_in[11];
    const float* W_c1   = (const float*)d_in[12];
    const float* b_c1   = (const float*)d_in[13];
    const float* W_c2   = (const float*)d_in[14];
    const float* W_n1   = (const float*)d_in[15];
    const float* b_n1   = (const float*)d_in[16];
    const float* W_n2   = (const float*)d_in[17];
    const float* b_n2   = (const float*)d_in[18];
    const float* ln_g   = (const float*)d_in[19];
    const float* ln_b   = (const float*)d_in[20];

    float* wsf  = (float*)d_ws;
    float* ca   = wsf;
    float* deg  = ca + 160000;
    float* agg  = deg + 10000;
    float* xacc = agg + (size_t)NN * RR * HH;
    float* hbuf = xacc + 120000;
    float* xbuf = hbuf + (size_t)NN * HH;
    ushort_t* ub = (ushort_t*)(xbuf + 120000);
    ushort_t* hb16  = ub;
    ushort_t* cab16 = hb16 + 2560000;
    ushort_t* pe1   = cab16 + 160000;
    ushort_t* pe2   = pe1 + 294912;
    ushort_t* pc1   = pe2 + 131072;
    ushort_t* pc2   = pc1 + 131072;
    ushort_t* pn1   = pc2 + 8192;
    ushort_t* pn2   = pn1 + 1048576;

    hipMemsetAsync(deg, 0, (size_t)NN * sizeof(float), stream);
    ca_kernel<<<(NN * CF + 255) / 256, 256, 0, stream>>>(cattr, cwts, ca);
    deg_kernel<<<(EE + 255) / 256, 256, 0, stream>>>(elist, deg);
    cvt_kernel<<<(NN * HH + 255) / 256, 256, 0, stream>>>(input, hb16, NN * HH);
    cvt_kernel<<<(NN * CF + 255) / 256, 256, 0, stream>>>(ca, cab16, NN * CF);

    for (int l = 0; l < 2; ++l) {
        pack_kernel<<<dim3(18, 16), 64, 0, stream>>>(W_e1 + (size_t)l * 560 * 256, pe1 + (size_t)l * 147456, 560, 256);
        pack_kernel<<<dim3(8, 16), 64, 0, stream>>>(W_e2 + (size_t)l * 65536, pe2 + (size_t)l * 65536, 256, 256);
        pack_kernel<<<dim3(8, 16), 64, 0, stream>>>(W_c1 + (size_t)l * 65536, pc1 + (size_t)l * 65536, 256, 256);
        pack_kernel<<<dim3(8, 1),  64, 0, stream>>>(W_c2 + (size_t)l * 4096,  pc2 + (size_t)l * 4096,  256, 16);
        pack_kernel<<<dim3(64, 16), 64, 0, stream>>>(W_n1 + (size_t)l * 524288, pn1 + (size_t)l * 524288, 2048, 256);
        pack_kernel<<<dim3(8, 16), 64, 0, stream>>>(W_n2 + (size_t)l * 65536, pn2 + (size_t)l * 65536, 256, 256);
    }

    for (int l = 0; l < 2; ++l) {
        const float* x_in = (l == 0) ? coords : xbuf;
        const float* h_in_f = (l == 0) ? input : hbuf;
        float* h_out = (l == 0) ? hbuf : (float*)d_out;
        float* x_out = (l == 0) ? xbuf : ((float*)d_out + (size_t)NN * HH);

        hipMemsetAsync(agg, 0, (size_t)NN * RR * HH * sizeof(float), stream);
        hipMemsetAsync(xacc, 0, (size_t)NN * 12 * sizeof(float), stream);

        edge_kernel<<<EE / 16, 256, 0, stream>>>(
            elist, cwts, ewts, x_in, hb16, cab16,
            W_rad + l * 256, b_rad + l * 16,
            pe1 + (size_t)l * 147456, b_e1 + l * HH,
            pe2 + (size_t)l * 65536,  b_e2 + l * HH,
            pc1 + (size_t)l * 65536,  b_c1 + l * HH,
            pc2 + (size_t)l * 4096,
            agg, xacc);

        node_kernel<<<NN / 16, 256, 0, stream>>>(
            agg, h_in_f,
            pn1 + (size_t)l * 524288, b_n1 + l * HH,
            pn2 + (size_t)l * 65536,  b_n2 + l * HH,
            ln_g + l * HH, ln_b + l * HH,
            h_out, hb16);

        xout_kernel<<<(NN * 12 + 255) / 256, 256, 0, stream>>>(
            x_in, xacc, deg, x_out);
    }
}

// Round 5
// 655.910 us; speedup vs baseline: 1.3982x; 1.3982x over previous
//
#include <hip/hip_runtime.h>
#include <hip/hip_bf16.h>

#define NN 10000
#define EE 160000
#define CCH 4
#define CF 16
#define RR 7
#define HH 256
#define NSEG 70000           // N*R
#define SCB 274              // ceil(NSEG/256)
#define EPSV 1e-5f

typedef unsigned short ushort_t;
typedef __bf16 bf16x8 __attribute__((ext_vector_type(8)));
typedef float f32x4 __attribute__((ext_vector_type(4)));

// fast silu: v * rcp(1 + exp2(-v*log2e))
__device__ __forceinline__ float silu_f(float v) {
    float e = __builtin_amdgcn_exp2f(v * -1.442695040888963f);
    return v * __builtin_amdgcn_rcpf(1.f + e);
}

__device__ __forceinline__ ushort_t bf16u(float f) {
    unsigned int u = __builtin_bit_cast(unsigned int, f);
    u += 0x7fffu + ((u >> 16) & 1u);
    return (ushort_t)(u >> 16);
}

__device__ __forceinline__ float ubf2f(ushort_t u) {
    unsigned int v = ((unsigned int)u) << 16;
    return __builtin_bit_cast(float, v);
}

// ---------------- prep kernels ----------------

__global__ __launch_bounds__(256) void ca_kernel(
    const float* __restrict__ attr, const float* __restrict__ cw,
    float* __restrict__ ca)
{
    int t = blockIdx.x * 256 + threadIdx.x;
    if (t < NN * CF) {
        int n = t >> 4, f = t & 15;
        float s = 0.f, cs = 0.f;
        #pragma unroll
        for (int c = 0; c < CCH; ++c) {
            float w = cw[n * CCH + c];
            s  += attr[(n * CCH + c) * CF + f] * w;
            cs += w;
        }
        ca[t] = s / cs;
    }
}

__global__ __launch_bounds__(256) void deg_kernel(
    const int* __restrict__ el, float* __restrict__ deg)
{
    int e = blockIdx.x * 256 + threadIdx.x;
    if (e < EE) atomicAdd(&deg[el[e * 3]], 1.f);
}

__global__ __launch_bounds__(256) void cvt_kernel(
    const float* __restrict__ s, ushort_t* __restrict__ d, int n)
{
    int t = blockIdx.x * 256 + threadIdx.x;
    if (t < n) d[t] = bf16u(s[t]);
}

// ---------------- counting sort of edges by seg = col*R + rel ----------------

__global__ __launch_bounds__(256) void hist_kernel(
    const int* __restrict__ el, int* __restrict__ hist)
{
    int e = blockIdx.x * 256 + threadIdx.x;
    if (e < EE) atomicAdd(&hist[el[e * 3 + 1] * RR + el[e * 3 + 2]], 1);
}

__global__ __launch_bounds__(256) void scan1_kernel(
    const int* __restrict__ hist, int* __restrict__ pscan, int* __restrict__ bsum)
{
    __shared__ int sc[256];
    int b = blockIdx.x, t = threadIdx.x, i = b * 256 + t;
    int v = (i < NSEG) ? hist[i] : 0;
    sc[t] = v; __syncthreads();
    for (int off = 1; off < 256; off <<= 1) {
        int u = (t >= off) ? sc[t - off] : 0;
        __syncthreads();
        sc[t] += u;
        __syncthreads();
    }
    if (i < NSEG) pscan[i] = sc[t] - v;   // exclusive within block
    if (t == 255) bsum[b] = sc[255];
}

__global__ void scan2_kernel(const int* __restrict__ bsum, int* __restrict__ bofs)
{
    if (threadIdx.x == 0) {
        int a = 0;
        for (int b = 0; b < SCB; ++b) { bofs[b] = a; a += bsum[b]; }
    }
}

__global__ __launch_bounds__(256) void scan3_kernel(
    const int* __restrict__ pscan, const int* __restrict__ bofs, int* __restrict__ segst)
{
    int b = blockIdx.x, t = threadIdx.x, i = b * 256 + t;
    if (i < NSEG) segst[i] = pscan[i] + bofs[b];
    if (i == 0) segst[NSEG] = EE;
}

__global__ __launch_bounds__(256) void scatter_kernel(
    const int* __restrict__ el, const int* __restrict__ segst,
    int* __restrict__ cursor, int* __restrict__ perm)
{
    int e = blockIdx.x * 256 + threadIdx.x;
    if (e < EE) {
        int s = el[e * 3 + 1] * RR + el[e * 3 + 2];
        int pos = segst[s] + atomicAdd(&cursor[s], 1);
        perm[pos] = e;
    }
}

// Pack W (Kreal x N row-major fp32) into MFMA B-fragment order, bf16.
__global__ __launch_bounds__(64) void pack_kernel(
    const float* __restrict__ W, ushort_t* __restrict__ out,
    int Kreal, int N)
{
    int kt = blockIdx.x, nt = blockIdx.y, NTOT = gridDim.y;
    int lane = threadIdx.x;
    int n = nt * 16 + (lane & 15);
    int kbase = kt * 32 + (lane >> 4) * 8;
    ushort_t* o = out + ((size_t)(kt * NTOT + nt) * 64 + lane) * 8;
    #pragma unroll
    for (int j = 0; j < 8; ++j) {
        int k = kbase + j;
        o[j] = (k < Kreal) ? bf16u(W[(size_t)k * N + n]) : (ushort_t)0;
    }
}

// ---------------- MFMA stage helper (32-edge M-tile) ----------------

template<int KT, int NTOT>
__device__ __forceinline__ void mfma_stage32(
    const ushort_t (&A)[32][584], int colOff,
    const ushort_t* __restrict__ Wp, int w, int lane,
    f32x4 (&acc)[2][4])
{
    const f32x4 Z = {0.f, 0.f, 0.f, 0.f};
    #pragma unroll
    for (int mt = 0; mt < 2; ++mt)
        #pragma unroll
        for (int j = 0; j < 4; ++j) acc[mt][j] = Z;
    const int ar = lane & 15, aq = (lane >> 4) * 8;
    for (int kt = 0; kt < KT; ++kt) {
        bf16x8 a0 = *(const bf16x8*)&A[ar][colOff + kt * 32 + aq];
        bf16x8 a1 = *(const bf16x8*)&A[16 + ar][colOff + kt * 32 + aq];
        #pragma unroll
        for (int j = 0; j < 4; ++j) {
            bf16x8 b = *(const bf16x8*)(Wp + ((size_t)(kt * NTOT + w * 4 + j) * 64 + lane) * 8);
            acc[0][j] = __builtin_amdgcn_mfma_f32_16x16x32_bf16(a0, b, acc[0][j], 0, 0, 0);
            acc[1][j] = __builtin_amdgcn_mfma_f32_16x16x32_bf16(a1, b, acc[1][j], 0, 0, 0);
        }
    }
}

// ---------------- fused edge kernel (32 sorted edges/block, 4 blk/CU) ----------

__global__ __launch_bounds__(256, 4) void edge_kernel(
    const int* __restrict__ el, const int* __restrict__ perm,
    const float* __restrict__ cw,
    const float* __restrict__ ew, const float* __restrict__ x,
    const ushort_t* __restrict__ hb16, const ushort_t* __restrict__ cab16,
    const float* __restrict__ W_rad, const float* __restrict__ b_rad,
    const ushort_t* __restrict__ pe1, const float* __restrict__ b_e1,
    const ushort_t* __restrict__ pe2, const float* __restrict__ b_e2,
    const ushort_t* __restrict__ pc1, const float* __restrict__ b_c1,
    const ushort_t* __restrict__ pc2,
    ushort_t* __restrict__ mb16, float* __restrict__ xacc)
{
    // Region map per row: X = cols 0..255, Y = cols 288..543.
    // e1 reads 0..575 -> t1 in Y -> e2 reads Y, m -> X -> c1 reads X,
    // t2 -> Y -> c2 reads Y. m (X) stored to mb16 in sorted-edge order.
    __shared__ ushort_t abuf[32][584];
    __shared__ float radbuf[32][16];     // radial, later phi
    __shared__ int rowS[32], colS[32];
    __shared__ float ewS[32];

    const int tid = threadIdx.x, lane = tid & 63, w = tid >> 6;
    const int ar = lane & 15, aq = (lane >> 4) * 8, quad = lane >> 4;
    const int e0 = blockIdx.x * 32;

    if (tid < 32) {
        int eg = perm[e0 + tid];
        rowS[tid] = el[eg * 3 + 0];
        colS[tid] = el[eg * 3 + 1];
        ewS[tid]  = ew[eg];
    }
    __syncthreads();   // B1

    // ---- staging: h, ca, pad, radial ----
    #pragma unroll
    for (int it = 0; it < 8; ++it) {
        int c = it * 256 + tid;
        int e = c >> 6, half = (c >> 5) & 1, idx = c & 31;
        int node = half ? colS[e] : rowS[e];
        *(uint4*)&abuf[e][half * 256 + idx * 8] =
            ((const uint4*)(hb16 + (size_t)node * 256))[idx];
    }
    if (tid < 128) {
        int e = tid >> 2, half2 = (tid >> 1) & 1, idx = tid & 1;
        int node = half2 ? colS[e] : rowS[e];
        *(uint4*)&abuf[e][528 + half2 * 16 + idx * 8] =
            ((const uint4*)(cab16 + node * 16))[idx];
    } else if (tid < 192) {
        int c = tid - 128, e = c >> 1, idx = c & 1;
        uint4 z = {0u, 0u, 0u, 0u};
        *(uint4*)&abuf[e][560 + idx * 8] = z;
    }
    #pragma unroll
    for (int it = 0; it < 2; ++it) {
        int t = it * 256 + tid;
        int e = t >> 4, ab = t & 15, a = ab >> 2, b = ab & 3;
        int row = rowS[e], col = colS[e];
        float d0 = x[row * 12 + a * 3 + 0] - x[col * 12 + b * 3 + 0];
        float d1 = x[row * 12 + a * 3 + 1] - x[col * 12 + b * 3 + 1];
        float d2 = x[row * 12 + a * 3 + 2] - x[col * 12 + b * 3 + 2];
        radbuf[e][ab] = (d0 * d0 + d1 * d1 + d2 * d2)
                      * cw[row * CCH + a] * cw[col * CCH + b];
    }
    __syncthreads();   // B2

    // rad_feat -> abuf cols 512..527
    #pragma unroll
    for (int it = 0; it < 2; ++it) {
        int t = it * 256 + tid;
        int e = t >> 4, f = t & 15;
        float acc = b_rad[f];
        #pragma unroll
        for (int ab = 0; ab < 16; ++ab) acc += radbuf[e][ab] * W_rad[ab * 16 + f];
        abuf[e][512 + f] = bf16u(silu_f(acc));
    }
    __syncthreads();   // B3

    f32x4 acc[2][4];

    // ---- e1: reads cols 0..575 ----
    mfma_stage32<18, 16>(abuf, 0, pe1, w, lane, acc);
    __syncthreads();   // B4
    #pragma unroll
    for (int j = 0; j < 4; ++j) {
        int n = w * 64 + j * 16 + ar;
        float bj = b_e1[n];
        #pragma unroll
        for (int mt = 0; mt < 2; ++mt)
            #pragma unroll
            for (int r = 0; r < 4; ++r)
                abuf[mt * 16 + quad * 4 + r][288 + n] = bf16u(silu_f(acc[mt][j][r] + bj));
    }
    __syncthreads();   // B5

    // ---- e2: reads Y, writes m -> X (disjoint) ----
    mfma_stage32<8, 16>(abuf, 288, pe2, w, lane, acc);
    #pragma unroll
    for (int j = 0; j < 4; ++j) {
        int n = w * 64 + j * 16 + ar;
        float bj = b_e2[n];
        #pragma unroll
        for (int mt = 0; mt < 2; ++mt)
            #pragma unroll
            for (int r = 0; r < 4; ++r) {
                int e = mt * 16 + quad * 4 + r;
                abuf[e][n] = bf16u(silu_f(acc[mt][j][r] + bj) * ewS[e]);
            }
    }
    __syncthreads();   // B6

    // ---- store m rows to mb16 (sorted order, coalesced, no RMW) ----
    #pragma unroll
    for (int it = 0; it < 4; ++it) {
        int t = it * 256 + tid;          // 1024 uint4 = 32 rows x 32
        int e = t >> 5, c = t & 31;
        *(uint4*)(mb16 + ((size_t)(e0 + e) * 256 + c * 8)) =
            *(const uint4*)&abuf[e][c * 8];
    }

    // ---- c1: reads X, writes t2 -> Y ----
    mfma_stage32<8, 16>(abuf, 0, pc1, w, lane, acc);
    #pragma unroll
    for (int j = 0; j < 4; ++j) {
        int n = w * 64 + j * 16 + ar;
        float bj = b_c1[n];
        #pragma unroll
        for (int mt = 0; mt < 2; ++mt)
            #pragma unroll
            for (int r = 0; r < 4; ++r)
                abuf[mt * 16 + quad * 4 + r][288 + n] = bf16u(silu_f(acc[mt][j][r] + bj));
    }
    __syncthreads();   // B7

    // ---- c2: waves 0,1 compute phi for 16 edges each -> radbuf ----
    if (w < 2) {
        const f32x4 Z = {0.f, 0.f, 0.f, 0.f};
        f32x4 p = Z;
        #pragma unroll
        for (int kt = 0; kt < 8; ++kt) {
            bf16x8 a = *(const bf16x8*)&abuf[w * 16 + ar][288 + kt * 32 + aq];
            bf16x8 b = *(const bf16x8*)(pc2 + ((size_t)kt * 64 + lane) * 8);
            p = __builtin_amdgcn_mfma_f32_16x16x32_bf16(a, b, p, 0, 0, 0);
        }
        #pragma unroll
        for (int r = 0; r < 4; ++r)
            radbuf[w * 16 + quad * 4 + r][ar] = p[r];
    }
    __syncthreads();   // B8

    // ---- trans -> xacc ----
    for (int t = tid; t < 384; t += 256) {
        int e = t / 12, r = t - e * 12, a = r / 3, k = r - a * 3;
        int row = rowS[e], col = colS[e];
        float xr = x[row * 12 + a * 3 + k];
        float s = 0.f;
        #pragma unroll
        for (int b = 0; b < 4; ++b)
            s += (xr - x[col * 12 + b * 3 + k]) * radbuf[e][a * 4 + b];
        atomicAdd(&xacc[row * 12 + a * 3 + k], 0.25f * s);
    }
}

// ---------------- segment-sum: agg[s] = sum of m rows in run, bf16 out --------

__global__ __launch_bounds__(256) void segsum_kernel(
    const ushort_t* __restrict__ mb16, const int* __restrict__ segst,
    ushort_t* __restrict__ aggb)
{
    int w = threadIdx.x >> 6, lane = threadIdx.x & 63;
    int s = blockIdx.x * 4 + w;
    if (s >= NSEG) return;
    int beg = segst[s], end = segst[s + 1];
    float a0 = 0.f, a1 = 0.f, a2 = 0.f, a3 = 0.f;
    for (int e = beg; e < end; ++e) {
        ushort4 u = *(const ushort4*)(mb16 + (size_t)e * 256 + lane * 4);
        a0 += ubf2f(u.x); a1 += ubf2f(u.y); a2 += ubf2f(u.z); a3 += ubf2f(u.w);
    }
    ushort4 o;
    o.x = bf16u(a0); o.y = bf16u(a1); o.z = bf16u(a2); o.w = bf16u(a3);
    *(ushort4*)(aggb + (size_t)s * 256 + lane * 4) = o;
}

// ---------------- fused node kernel (bf16 agg + bf16 h sources) ---------------

__global__ __launch_bounds__(256, 3) void node_kernel(
    const ushort_t* __restrict__ aggb,
    const ushort_t* __restrict__ pn1, const float* __restrict__ b_n1,
    const ushort_t* __restrict__ pn2, const float* __restrict__ b_n2,
    const float* __restrict__ ln_g, const float* __restrict__ ln_b,
    float* __restrict__ h_out, ushort_t* __restrict__ hb16)
{
    __shared__ __align__(16) char arena[33024];
    __shared__ ushort_t tbuf[16][264];
    __shared__ float redS[16][16], red2S[16][16], muS[16], rsS[16];
    ushort_t (*nbuf)[1032] = (ushort_t(*)[1032])arena;
    float (*h2buf)[264] = (float(*)[264])arena;

    const int tid = threadIdx.x, lane = tid & 63, w = tid >> 6;
    const int n0 = blockIdx.x * 16;
    const int ar = lane & 15, aq = (lane >> 4) * 8;
    const f32x4 Z = {0.f, 0.f, 0.f, 0.f};

    f32x4 acc[4] = {Z, Z, Z, Z};
    for (int chunk = 0; chunk < 2; ++chunk) {
        #pragma unroll
        for (int it = 0; it < 8; ++it) {
            int t = it * 256 + tid;      // 2048 uint4 = 16 nodes x 128
            int node = t >> 7, i4 = t & 127;
            int g4 = chunk * 128 + i4;   // uint4 idx over 2048 bf16
            uint4 v;
            if (g4 < 224) v = ((const uint4*)(aggb + (size_t)(n0 + node) * 1792))[g4];
            else          v = ((const uint4*)(hb16 + (size_t)(n0 + node) * 256))[g4 - 224];
            *(uint4*)&nbuf[node][i4 * 8] = v;
        }
        __syncthreads();
        for (int kt = 0; kt < 32; ++kt) {
            bf16x8 a = *(const bf16x8*)&nbuf[ar][kt * 32 + aq];
            int ktg = chunk * 32 + kt;
            #pragma unroll
            for (int j = 0; j < 4; ++j) {
                bf16x8 b = *(const bf16x8*)(pn1 + ((size_t)(ktg * 16 + w * 4 + j) * 64 + lane) * 8);
                acc[j] = __builtin_amdgcn_mfma_f32_16x16x32_bf16(a, b, acc[j], 0, 0, 0);
            }
        }
        __syncthreads();
    }
    #pragma unroll
    for (int j = 0; j < 4; ++j) {
        int n = w * 64 + j * 16 + ar;
        float bj = b_n1[n];
        #pragma unroll
        for (int r = 0; r < 4; ++r)
            tbuf[(lane >> 4) * 4 + r][n] = bf16u(silu_f(acc[j][r] + bj));
    }
    __syncthreads();
    f32x4 acc2[4] = {Z, Z, Z, Z};
    for (int kt = 0; kt < 8; ++kt) {
        bf16x8 a = *(const bf16x8*)&tbuf[ar][kt * 32 + aq];
        #pragma unroll
        for (int j = 0; j < 4; ++j) {
            bf16x8 b = *(const bf16x8*)(pn2 + ((size_t)(kt * 16 + w * 4 + j) * 64 + lane) * 8);
            acc2[j] = __builtin_amdgcn_mfma_f32_16x16x32_bf16(a, b, acc2[j], 0, 0, 0);
        }
    }
    float hv[4][4];
    #pragma unroll
    for (int j = 0; j < 4; ++j) {
        int n = w * 64 + j * 16 + ar;
        float bj = b_n2[n];
        #pragma unroll
        for (int r = 0; r < 4; ++r) {
            hv[j][r] = acc2[j][r] + bj;
            h2buf[(lane >> 4) * 4 + r][n] = hv[j][r];
        }
    }
    __syncthreads();
    {
        int node = tid >> 4, c = tid & 15;
        float s = 0.f, s2 = 0.f;
        #pragma unroll
        for (int i = 0; i < 16; ++i) {
            float v = h2buf[node][c * 16 + i];
            s += v; s2 += v * v;
        }
        redS[node][c] = s; red2S[node][c] = s2;
    }
    __syncthreads();
    if (tid < 16) {
        float s = 0.f, s2 = 0.f;
        #pragma unroll
        for (int c = 0; c < 16; ++c) { s += redS[tid][c]; s2 += red2S[tid][c]; }
        float mu = s * (1.f / 256.f);
        muS[tid] = mu;
        rsS[tid] = rsqrtf(s2 * (1.f / 256.f) - mu * mu + EPSV);
    }
    __syncthreads();
    #pragma unroll
    for (int j = 0; j < 4; ++j) {
        int n = w * 64 + j * 16 + ar;
        float g = ln_g[n], bb = ln_b[n];
        #pragma unroll
        for (int r = 0; r < 4; ++r) {
            int row = (lane >> 4) * 4 + r;
            float v = (hv[j][r] - muS[row]) * rsS[row] * g + bb;
            h_out[(size_t)(n0 + row) * HH + n] = v;
            hb16[(size_t)(n0 + row) * HH + n] = bf16u(v);
        }
    }
}

__global__ __launch_bounds__(256) void xout_kernel(
    const float* __restrict__ x_in, const float* __restrict__ xacc,
    const float* __restrict__ deg, float* __restrict__ x_out)
{
    int t = blockIdx.x * 256 + threadIdx.x;
    if (t < NN * 12) {
        int n = t / 12;
        float c = fmaxf(deg[n], 1.f);
        x_out[t] = x_in[t] + xacc[t] / c;
    }
}

// ---------------- launcher ----------------

extern "C" void kernel_launch(void* const* d_in, const int* in_sizes, int n_in,
                              void* d_out, int out_size, void* d_ws, size_t ws_size,
                              hipStream_t stream)
{
    const float* input  = (const float*)d_in[0];
    const float* coords = (const float*)d_in[1];
    const float* cattr  = (const float*)d_in[2];
    const float* cwts   = (const float*)d_in[3];
    const float* ewts   = (const float*)d_in[4];
    const int*   elist  = (const int*)d_in[5];
    const float* W_rad  = (const float*)d_in[6];
    const float* b_rad  = (const float*)d_in[7];
    const float* W_e1   = (const float*)d_in[8];
    const float* b_e1   = (const float*)d_in[9];
    const float* W_e2   = (const float*)d_in[10];
    const float* b_e2   = (const float*)d_in[11];
    const float* W_c1   = (const float*)d_in[12];
    const float* b_c1   = (const float*)d_in[13];
    const float* W_c2   = (const float*)d_in[14];
    const float* W_n1   = (const float*)d_in[15];
    const float* b_n1   = (const float*)d_in[16];
    const float* W_n2   = (const float*)d_in[17];
    const float* b_n2   = (const float*)d_in[18];
    const float* ln_g   = (const float*)d_in[19];
    const float* ln_b   = (const float*)d_in[20];

    float* wsf  = (float*)d_ws;
    float* ca   = wsf;                    // 160000
    float* deg  = ca + 160000;            // 10000
    float* xacc = deg + 10000;            // 120000
    float* xbuf = xacc + 120000;          // 120000
    int* ip     = (int*)(xbuf + 120000);
    int* hist   = ip;                     // 70000
    int* pscan  = hist + 70000;           // 70000
    int* cursor = pscan + 70000;          // 70000
    int* segst  = cursor + 70000;         // 70001
    int* bsum   = segst + 70001;          // 280
    int* bofs   = bsum + 280;             // 280
    int* perm   = bofs + 280;             // 160000
    ushort_t* up = (ushort_t*)(((uintptr_t)(perm + 160000) + 15) & ~(uintptr_t)15);
    ushort_t* hb16  = up;                 // 2,560,000
    ushort_t* cab16 = hb16 + 2560000;     // 160,000
    ushort_t* mb16  = cab16 + 160000;     // 40,960,000
    ushort_t* aggb  = mb16 + 40960000;    // 17,920,000
    ushort_t* pe1   = aggb + 17920000;    // 2 x 147456
    ushort_t* pe2   = pe1 + 294912;       // 2 x 65536
    ushort_t* pc1   = pe2 + 131072;       // 2 x 65536
    ushort_t* pc2   = pc1 + 131072;       // 2 x 4096
    ushort_t* pn1   = pc2 + 8192;         // 2 x 524288
    ushort_t* pn2   = pn1 + 1048576;      // 2 x 65536

    hipMemsetAsync(deg, 0, (size_t)NN * sizeof(float), stream);
    hipMemsetAsync(hist, 0, (size_t)NSEG * sizeof(int), stream);
    hipMemsetAsync(cursor, 0, (size_t)NSEG * sizeof(int), stream);

    ca_kernel<<<(NN * CF + 255) / 256, 256, 0, stream>>>(cattr, cwts, ca);
    deg_kernel<<<(EE + 255) / 256, 256, 0, stream>>>(elist, deg);
    cvt_kernel<<<(NN * HH + 255) / 256, 256, 0, stream>>>(input, hb16, NN * HH);
    cvt_kernel<<<(NN * CF + 255) / 256, 256, 0, stream>>>(ca, cab16, NN * CF);

    // counting sort by seg
    hist_kernel<<<(EE + 255) / 256, 256, 0, stream>>>(elist, hist);
    scan1_kernel<<<SCB, 256, 0, stream>>>(hist, pscan, bsum);
    scan2_kernel<<<1, 64, 0, stream>>>(bsum, bofs);
    scan3_kernel<<<SCB, 256, 0, stream>>>(pscan, bofs, segst);
    scatter_kernel<<<(EE + 255) / 256, 256, 0, stream>>>(elist, segst, cursor, perm);

    for (int l = 0; l < 2; ++l) {
        pack_kernel<<<dim3(18, 16), 64, 0, stream>>>(W_e1 + (size_t)l * 560 * 256, pe1 + (size_t)l * 147456, 560, 256);
        pack_kernel<<<dim3(8, 16), 64, 0, stream>>>(W_e2 + (size_t)l * 65536, pe2 + (size_t)l * 65536, 256, 256);
        pack_kernel<<<dim3(8, 16), 64, 0, stream>>>(W_c1 + (size_t)l * 65536, pc1 + (size_t)l * 65536, 256, 256);
        pack_kernel<<<dim3(8, 1),  64, 0, stream>>>(W_c2 + (size_t)l * 4096,  pc2 + (size_t)l * 4096,  256, 16);
        pack_kernel<<<dim3(64, 16), 64, 0, stream>>>(W_n1 + (size_t)l * 524288, pn1 + (size_t)l * 524288, 2048, 256);
        pack_kernel<<<dim3(8, 16), 64, 0, stream>>>(W_n2 + (size_t)l * 65536, pn2 + (size_t)l * 65536, 256, 256);
    }

    for (int l = 0; l < 2; ++l) {
        const float* x_in = (l == 0) ? coords : xbuf;
        float* h_out = (float*)d_out;     // layer0 fp32 h never read; overwritten by layer1
        float* x_out = (l == 0) ? xbuf : ((float*)d_out + (size_t)NN * HH);

        hipMemsetAsync(xacc, 0, (size_t)NN * 12 * sizeof(float), stream);

        edge_kernel<<<EE / 32, 256, 0, stream>>>(
            elist, perm, cwts, ewts, x_in, hb16, cab16,
            W_rad + l * 256, b_rad + l * 16,
            pe1 + (size_t)l * 147456, b_e1 + l * HH,
            pe2 + (size_t)l * 65536,  b_e2 + l * HH,
            pc1 + (size_t)l * 65536,  b_c1 + l * HH,
            pc2 + (size_t)l * 4096,
            mb16, xacc);

        segsum_kernel<<<(NSEG + 3) / 4, 256, 0, stream>>>(mb16, segst, aggb);

        node_kernel<<<NN / 16, 256, 0, stream>>>(
            aggb,
            pn1 + (size_t)l * 524288, b_n1 + l * HH,
            pn2 + (size_t)l * 65536,  b_n2 + l * HH,
            ln_g + l * HH, ln_b + l * HH,
            h_out, hb16);

        xout_kernel<<<(NN * 12 + 255) / 256, 256, 0, stream>>>(
            x_in, xacc, deg, x_out);
    }
}

// Round 7
// 653.088 us; speedup vs baseline: 1.4043x; 1.0043x over previous
//
#include <hip/hip_runtime.h>
#include <hip/hip_bf16.h>

#define NN 10000
#define EE 160000
#define CCH 4
#define CF 16
#define RR 7
#define HH 256
#define NSEG 70000           // N*R
#define SCB 274              // ceil(NSEG/256)
#define EPSV 1e-5f

typedef unsigned short ushort_t;
typedef __bf16 bf16x8 __attribute__((ext_vector_type(8)));
typedef float f32x4 __attribute__((ext_vector_type(4)));

// fast silu: v * rcp(1 + exp2(-v*log2e))
__device__ __forceinline__ float silu_f(float v) {
    float e = __builtin_amdgcn_exp2f(v * -1.442695040888963f);
    return v * __builtin_amdgcn_rcpf(1.f + e);
}

__device__ __forceinline__ ushort_t bf16u(float f) {
    unsigned int u = __builtin_bit_cast(unsigned int, f);
    u += 0x7fffu + ((u >> 16) & 1u);
    return (ushort_t)(u >> 16);
}

__device__ __forceinline__ float ubf2f(ushort_t u) {
    unsigned int v = ((unsigned int)u) << 16;
    return __builtin_bit_cast(float, v);
}

// ---------------- prep kernels ----------------

__global__ __launch_bounds__(256) void ca_kernel(
    const float* __restrict__ attr, const float* __restrict__ cw,
    float* __restrict__ ca)
{
    int t = blockIdx.x * 256 + threadIdx.x;
    if (t < NN * CF) {
        int n = t >> 4, f = t & 15;
        float s = 0.f, cs = 0.f;
        #pragma unroll
        for (int c = 0; c < CCH; ++c) {
            float w = cw[n * CCH + c];
            s  += attr[(n * CCH + c) * CF + f] * w;
            cs += w;
        }
        ca[t] = s / cs;
    }
}

__global__ __launch_bounds__(256) void deg_kernel(
    const int* __restrict__ el, float* __restrict__ deg)
{
    int e = blockIdx.x * 256 + threadIdx.x;
    if (e < EE) atomicAdd(&deg[el[e * 3]], 1.f);
}

__global__ __launch_bounds__(256) void cvt_kernel(
    const float* __restrict__ s, ushort_t* __restrict__ d, int n)
{
    int t = blockIdx.x * 256 + threadIdx.x;
    if (t < n) d[t] = bf16u(s[t]);
}

// ---------------- counting sort of edges by seg = col*R + rel ----------------

__global__ __launch_bounds__(256) void hist_kernel(
    const int* __restrict__ el, int* __restrict__ hist)
{
    int e = blockIdx.x * 256 + threadIdx.x;
    if (e < EE) atomicAdd(&hist[el[e * 3 + 1] * RR + el[e * 3 + 2]], 1);
}

__global__ __launch_bounds__(256) void scan1_kernel(
    const int* __restrict__ hist, int* __restrict__ pscan, int* __restrict__ bsum)
{
    __shared__ int sc[256];
    int b = blockIdx.x, t = threadIdx.x, i = b * 256 + t;
    int v = (i < NSEG) ? hist[i] : 0;
    sc[t] = v; __syncthreads();
    for (int off = 1; off < 256; off <<= 1) {
        int u = (t >= off) ? sc[t - off] : 0;
        __syncthreads();
        sc[t] += u;
        __syncthreads();
    }
    if (i < NSEG) pscan[i] = sc[t] - v;   // exclusive within block
    if (t == 255) bsum[b] = sc[255];
}

__global__ void scan2_kernel(const int* __restrict__ bsum, int* __restrict__ bofs)
{
    if (threadIdx.x == 0) {
        int a = 0;
        for (int b = 0; b < SCB; ++b) { bofs[b] = a; a += bsum[b]; }
    }
}

__global__ __launch_bounds__(256) void scan3_kernel(
    const int* __restrict__ pscan, const int* __restrict__ bofs, int* __restrict__ segst)
{
    int b = blockIdx.x, t = threadIdx.x, i = b * 256 + t;
    if (i < NSEG) segst[i] = pscan[i] + bofs[b];
    if (i == 0) segst[NSEG] = EE;
}

__global__ __launch_bounds__(256) void scatter_kernel(
    const int* __restrict__ el, const int* __restrict__ segst,
    int* __restrict__ cursor, int* __restrict__ perm)
{
    int e = blockIdx.x * 256 + threadIdx.x;
    if (e < EE) {
        int s = el[e * 3 + 1] * RR + el[e * 3 + 2];
        int pos = segst[s] + atomicAdd(&cursor[s], 1);
        perm[pos] = e;
    }
}

// Pack W (Kreal x N row-major fp32) into MFMA B-fragment order, bf16.
__global__ __launch_bounds__(64) void pack_kernel(
    const float* __restrict__ W, ushort_t* __restrict__ out,
    int Kreal, int N)
{
    int kt = blockIdx.x, nt = blockIdx.y, NTOT = gridDim.y;
    int lane = threadIdx.x;
    int n = nt * 16 + (lane & 15);
    int kbase = kt * 32 + (lane >> 4) * 8;
    ushort_t* o = out + ((size_t)(kt * NTOT + nt) * 64 + lane) * 8;
    #pragma unroll
    for (int j = 0; j < 8; ++j) {
        int k = kbase + j;
        o[j] = (k < Kreal) ? bf16u(W[(size_t)k * N + n]) : (ushort_t)0;
    }
}

// ---------------- MFMA stage helper (32-edge M-tile) ----------------

template<int KT, int NTOT>
__device__ __forceinline__ void mfma_stage32(
    const ushort_t (&A)[32][584], int colOff,
    const ushort_t* __restrict__ Wp, int w, int lane,
    f32x4 (&acc)[2][4])
{
    const f32x4 Z = {0.f, 0.f, 0.f, 0.f};
    #pragma unroll
    for (int mt = 0; mt < 2; ++mt)
        #pragma unroll
        for (int j = 0; j < 4; ++j) acc[mt][j] = Z;
    const int ar = lane & 15, aq = (lane >> 4) * 8;
    for (int kt = 0; kt < KT; ++kt) {
        bf16x8 a0 = *(const bf16x8*)&A[ar][colOff + kt * 32 + aq];
        bf16x8 a1 = *(const bf16x8*)&A[16 + ar][colOff + kt * 32 + aq];
        #pragma unroll
        for (int j = 0; j < 4; ++j) {
            bf16x8 b = *(const bf16x8*)(Wp + ((size_t)(kt * NTOT + w * 4 + j) * 64 + lane) * 8);
            acc[0][j] = __builtin_amdgcn_mfma_f32_16x16x32_bf16(a0, b, acc[0][j], 0, 0, 0);
            acc[1][j] = __builtin_amdgcn_mfma_f32_16x16x32_bf16(a1, b, acc[1][j], 0, 0, 0);
        }
    }
}

// ---------------- fused edge kernel (32 sorted edges/block, 4 blk/CU) ----------
// (R4 known-good structure, unchanged)

__global__ __launch_bounds__(256, 4) void edge_kernel(
    const int* __restrict__ el, const int* __restrict__ perm,
    const float* __restrict__ cw,
    const float* __restrict__ ew, const float* __restrict__ x,
    const ushort_t* __restrict__ hb16, const ushort_t* __restrict__ cab16,
    const float* __restrict__ W_rad, const float* __restrict__ b_rad,
    const ushort_t* __restrict__ pe1, const float* __restrict__ b_e1,
    const ushort_t* __restrict__ pe2, const float* __restrict__ b_e2,
    const ushort_t* __restrict__ pc1, const float* __restrict__ b_c1,
    const ushort_t* __restrict__ pc2,
    ushort_t* __restrict__ mb16, float* __restrict__ xacc)
{
    // Region map per row: X = cols 0..255, Y = cols 288..543.
    __shared__ ushort_t abuf[32][584];
    __shared__ float radbuf[32][16];     // radial, later phi
    __shared__ int rowS[32], colS[32];
    __shared__ float ewS[32];

    const int tid = threadIdx.x, lane = tid & 63, w = tid >> 6;
    const int ar = lane & 15, aq = (lane >> 4) * 8, quad = lane >> 4;
    const int e0 = blockIdx.x * 32;

    if (tid < 32) {
        int eg = perm[e0 + tid];
        rowS[tid] = el[eg * 3 + 0];
        colS[tid] = el[eg * 3 + 1];
        ewS[tid]  = ew[eg];
    }
    __syncthreads();   // B1

    // ---- staging: h, ca, pad, radial ----
    #pragma unroll
    for (int it = 0; it < 8; ++it) {
        int c = it * 256 + tid;
        int e = c >> 6, half = (c >> 5) & 1, idx = c & 31;
        int node = half ? colS[e] : rowS[e];
        *(uint4*)&abuf[e][half * 256 + idx * 8] =
            ((const uint4*)(hb16 + (size_t)node * 256))[idx];
    }
    if (tid < 128) {
        int e = tid >> 2, half2 = (tid >> 1) & 1, idx = tid & 1;
        int node = half2 ? colS[e] : rowS[e];
        *(uint4*)&abuf[e][528 + half2 * 16 + idx * 8] =
            ((const uint4*)(cab16 + node * 16))[idx];
    } else if (tid < 192) {
        int c = tid - 128, e = c >> 1, idx = c & 1;
        uint4 z = {0u, 0u, 0u, 0u};
        *(uint4*)&abuf[e][560 + idx * 8] = z;
    }
    #pragma unroll
    for (int it = 0; it < 2; ++it) {
        int t = it * 256 + tid;
        int e = t >> 4, ab = t & 15, a = ab >> 2, b = ab & 3;
        int row = rowS[e], col = colS[e];
        float d0 = x[row * 12 + a * 3 + 0] - x[col * 12 + b * 3 + 0];
        float d1 = x[row * 12 + a * 3 + 1] - x[col * 12 + b * 3 + 1];
        float d2 = x[row * 12 + a * 3 + 2] - x[col * 12 + b * 3 + 2];
        radbuf[e][ab] = (d0 * d0 + d1 * d1 + d2 * d2)
                      * cw[row * CCH + a] * cw[col * CCH + b];
    }
    __syncthreads();   // B2

    // rad_feat -> abuf cols 512..527
    #pragma unroll
    for (int it = 0; it < 2; ++it) {
        int t = it * 256 + tid;
        int e = t >> 4, f = t & 15;
        float acc = b_rad[f];
        #pragma unroll
        for (int ab = 0; ab < 16; ++ab) acc += radbuf[e][ab] * W_rad[ab * 16 + f];
        abuf[e][512 + f] = bf16u(silu_f(acc));
    }
    __syncthreads();   // B3

    f32x4 acc[2][4];

    // ---- e1: reads cols 0..575 ----
    mfma_stage32<18, 16>(abuf, 0, pe1, w, lane, acc);
    __syncthreads();   // B4
    #pragma unroll
    for (int j = 0; j < 4; ++j) {
        int n = w * 64 + j * 16 + ar;
        float bj = b_e1[n];
        #pragma unroll
        for (int mt = 0; mt < 2; ++mt)
            #pragma unroll
            for (int r = 0; r < 4; ++r)
                abuf[mt * 16 + quad * 4 + r][288 + n] = bf16u(silu_f(acc[mt][j][r] + bj));
    }
    __syncthreads();   // B5

    // ---- e2: reads Y, writes m -> X (disjoint) ----
    mfma_stage32<8, 16>(abuf, 288, pe2, w, lane, acc);
    #pragma unroll
    for (int j = 0; j < 4; ++j) {
        int n = w * 64 + j * 16 + ar;
        float bj = b_e2[n];
        #pragma unroll
        for (int mt = 0; mt < 2; ++mt)
            #pragma unroll
            for (int r = 0; r < 4; ++r) {
                int e = mt * 16 + quad * 4 + r;
                abuf[e][n] = bf16u(silu_f(acc[mt][j][r] + bj) * ewS[e]);
            }
    }
    __syncthreads();   // B6

    // ---- store m rows to mb16 (sorted order, coalesced, no RMW) ----
    #pragma unroll
    for (int it = 0; it < 4; ++it) {
        int t = it * 256 + tid;          // 1024 uint4 = 32 rows x 32
        int e = t >> 5, c = t & 31;
        *(uint4*)(mb16 + ((size_t)(e0 + e) * 256 + c * 8)) =
            *(const uint4*)&abuf[e][c * 8];
    }

    // ---- c1: reads X, writes t2 -> Y ----
    mfma_stage32<8, 16>(abuf, 0, pc1, w, lane, acc);
    #pragma unroll
    for (int j = 0; j < 4; ++j) {
        int n = w * 64 + j * 16 + ar;
        float bj = b_c1[n];
        #pragma unroll
        for (int mt = 0; mt < 2; ++mt)
            #pragma unroll
            for (int r = 0; r < 4; ++r)
                abuf[mt * 16 + quad * 4 + r][288 + n] = bf16u(silu_f(acc[mt][j][r] + bj));
    }
    __syncthreads();   // B7

    // ---- c2: waves 0,1 compute phi for 16 edges each -> radbuf ----
    if (w < 2) {
        const f32x4 Z = {0.f, 0.f, 0.f, 0.f};
        f32x4 p = Z;
        #pragma unroll
        for (int kt = 0; kt < 8; ++kt) {
            bf16x8 a = *(const bf16x8*)&abuf[w * 16 + ar][288 + kt * 32 + aq];
            bf16x8 b = *(const bf16x8*)(pc2 + ((size_t)kt * 64 + lane) * 8);
            p = __builtin_amdgcn_mfma_f32_16x16x32_bf16(a, b, p, 0, 0, 0);
        }
        #pragma unroll
        for (int r = 0; r < 4; ++r)
            radbuf[w * 16 + quad * 4 + r][ar] = p[r];
    }
    __syncthreads();   // B8

    // ---- trans -> xacc ----
    for (int t = tid; t < 384; t += 256) {
        int e = t / 12, r = t - e * 12, a = r / 3, k = r - a * 3;
        int row = rowS[e], col = colS[e];
        float xr = x[row * 12 + a * 3 + k];
        float s = 0.f;
        #pragma unroll
        for (int b = 0; b < 4; ++b)
            s += (xr - x[col * 12 + b * 3 + k]) * radbuf[e][a * 4 + b];
        atomicAdd(&xacc[row * 12 + a * 3 + k], 0.25f * s);
    }
}

// ---------------- fused node kernel (segsum + n1 + n2 + LN, 16 nodes/block) ----
// Node n's 7 segments are contiguous in sorted-edge order: positions
// segst[n*7] .. segst[n*7+7]. Chunk0 = segs 0..3 (K cols 0..1023),
// chunk1 = segs 4..6 + h row (K cols 1024..2047) -- same K mapping as before,
// pn1 packing unchanged. fp32 accumulate per seg, round once to bf16
// (bit-identical to the old segsum->aggb path).

__global__ __launch_bounds__(256, 3) void node_kernel(
    const ushort_t* __restrict__ mb16, const int* __restrict__ segst,
    const ushort_t* __restrict__ pn1, const float* __restrict__ b_n1,
    const ushort_t* __restrict__ pn2, const float* __restrict__ b_n2,
    const float* __restrict__ ln_g, const float* __restrict__ ln_b,
    float* __restrict__ h_out, ushort_t* __restrict__ hb16)
{
    __shared__ __align__(16) char arena[33024];
    __shared__ ushort_t tbuf[16][264];
    __shared__ float redS[16][16], red2S[16][16], muS[16], rsS[16];
    ushort_t (*nbuf)[1032] = (ushort_t(*)[1032])arena;
    float (*h2buf)[264] = (float(*)[264])arena;

    const int tid = threadIdx.x, lane = tid & 63, w = tid >> 6;
    const int n0 = blockIdx.x * 16;
    const int ar = lane & 15, aq = (lane >> 4) * 8;
    const f32x4 Z = {0.f, 0.f, 0.f, 0.f};

    f32x4 acc[4] = {Z, Z, Z, Z};
    for (int chunk = 0; chunk < 2; ++chunk) {
        // ---- staging: wave w handles nodes w*4 .. w*4+3 ----
        for (int ln = 0; ln < 4; ++ln) {
            int node = w * 4 + ln;
            int gnode = n0 + node;
            if (chunk == 0) {
                #pragma unroll
                for (int r = 0; r < 4; ++r) {
                    int s = gnode * RR + r;
                    int beg = segst[s], end = segst[s + 1];
                    float a0 = 0.f, a1 = 0.f, a2 = 0.f, a3 = 0.f;
                    for (int e = beg; e < end; ++e) {
                        ushort4 u = *(const ushort4*)(mb16 + (size_t)e * 256 + lane * 4);
                        a0 += ubf2f(u.x); a1 += ubf2f(u.y);
                        a2 += ubf2f(u.z); a3 += ubf2f(u.w);
                    }
                    ushort4 o;
                    o.x = bf16u(a0); o.y = bf16u(a1); o.z = bf16u(a2); o.w = bf16u(a3);
                    *(ushort4*)&nbuf[node][r * 256 + lane * 4] = o;
                }
            } else {
                #pragma unroll
                for (int r = 4; r < 7; ++r) {
                    int s = gnode * RR + r;
                    int beg = segst[s], end = segst[s + 1];
                    float a0 = 0.f, a1 = 0.f, a2 = 0.f, a3 = 0.f;
                    for (int e = beg; e < end; ++e) {
                        ushort4 u = *(const ushort4*)(mb16 + (size_t)e * 256 + lane * 4);
                        a0 += ubf2f(u.x); a1 += ubf2f(u.y);
                        a2 += ubf2f(u.z); a3 += ubf2f(u.w);
                    }
                    ushort4 o;
                    o.x = bf16u(a0); o.y = bf16u(a1); o.z = bf16u(a2); o.w = bf16u(a3);
                    *(ushort4*)&nbuf[node][(r - 4) * 256 + lane * 4] = o;
                }
                *(ushort4*)&nbuf[node][768 + lane * 4] =
                    *(const ushort4*)(hb16 + (size_t)gnode * 256 + lane * 4);
            }
        }
        __syncthreads();
        for (int kt = 0; kt < 32; ++kt) {
            bf16x8 a = *(const bf16x8*)&nbuf[ar][kt * 32 + aq];
            int ktg = chunk * 32 + kt;
            #pragma unroll
            for (int j = 0; j < 4; ++j) {
                bf16x8 b = *(const bf16x8*)(pn1 + ((size_t)(ktg * 16 + w * 4 + j) * 64 + lane) * 8);
                acc[j] = __builtin_amdgcn_mfma_f32_16x16x32_bf16(a, b, acc[j], 0, 0, 0);
            }
        }
        __syncthreads();
    }
    #pragma unroll
    for (int j = 0; j < 4; ++j) {
        int n = w * 64 + j * 16 + ar;
        float bj = b_n1[n];
        #pragma unroll
        for (int r = 0; r < 4; ++r)
            tbuf[(lane >> 4) * 4 + r][n] = bf16u(silu_f(acc[j][r] + bj));
    }
    __syncthreads();
    f32x4 acc2[4] = {Z, Z, Z, Z};
    for (int kt = 0; kt < 8; ++kt) {
        bf16x8 a = *(const bf16x8*)&tbuf[ar][kt * 32 + aq];
        #pragma unroll
        for (int j = 0; j < 4; ++j) {
            bf16x8 b = *(const bf16x8*)(pn2 + ((size_t)(kt * 16 + w * 4 + j) * 64 + lane) * 8);
            acc2[j] = __builtin_amdgcn_mfma_f32_16x16x32_bf16(a, b, acc2[j], 0, 0, 0);
        }
    }
    float hv[4][4];
    #pragma unroll
    for (int j = 0; j < 4; ++j) {
        int n = w * 64 + j * 16 + ar;
        float bj = b_n2[n];
        #pragma unroll
        for (int r = 0; r < 4; ++r) {
            hv[j][r] = acc2[j][r] + bj;
            h2buf[(lane >> 4) * 4 + r][n] = hv[j][r];
        }
    }
    __syncthreads();
    {
        int node = tid >> 4, c = tid & 15;
        float s = 0.f, s2 = 0.f;
        #pragma unroll
        for (int i = 0; i < 16; ++i) {
            float v = h2buf[node][c * 16 + i];
            s += v; s2 += v * v;
        }
        redS[node][c] = s; red2S[node][c] = s2;
    }
    __syncthreads();
    if (tid < 16) {
        float s = 0.f, s2 = 0.f;
        #pragma unroll
        for (int c = 0; c < 16; ++c) { s += redS[tid][c]; s2 += red2S[tid][c]; }
        float mu = s * (1.f / 256.f);
        muS[tid] = mu;
        rsS[tid] = rsqrtf(s2 * (1.f / 256.f) - mu * mu + EPSV);
    }
    __syncthreads();
    #pragma unroll
    for (int j = 0; j < 4; ++j) {
        int n = w * 64 + j * 16 + ar;
        float g = ln_g[n], bb = ln_b[n];
        #pragma unroll
        for (int r = 0; r < 4; ++r) {
            int row = (lane >> 4) * 4 + r;
            float v = (hv[j][r] - muS[row]) * rsS[row] * g + bb;
            h_out[(size_t)(n0 + row) * HH + n] = v;
            hb16[(size_t)(n0 + row) * HH + n] = bf16u(v);
        }
    }
}

__global__ __launch_bounds__(256) void xout_kernel(
    const float* __restrict__ x_in, const float* __restrict__ xacc,
    const float* __restrict__ deg, float* __restrict__ x_out)
{
    int t = blockIdx.x * 256 + threadIdx.x;
    if (t < NN * 12) {
        int n = t / 12;
        float c = fmaxf(deg[n], 1.f);
        x_out[t] = x_in[t] + xacc[t] / c;
    }
}

// ---------------- launcher ----------------

extern "C" void kernel_launch(void* const* d_in, const int* in_sizes, int n_in,
                              void* d_out, int out_size, void* d_ws, size_t ws_size,
                              hipStream_t stream)
{
    const float* input  = (const float*)d_in[0];
    const float* coords = (const float*)d_in[1];
    const float* cattr  = (const float*)d_in[2];
    const float* cwts   = (const float*)d_in[3];
    const float* ewts   = (const float*)d_in[4];
    const int*   elist  = (const int*)d_in[5];
    const float* W_rad  = (const float*)d_in[6];
    const float* b_rad  = (const float*)d_in[7];
    const float* W_e1   = (const float*)d_in[8];
    const float* b_e1   = (const float*)d_in[9];
    const float* W_e2   = (const float*)d_in[10];
    const float* b_e2   = (const float*)d_in[11];
    const float* W_c1   = (const float*)d_in[12];
    const float* b_c1   = (const float*)d_in[13];
    const float* W_c2   = (const float*)d_in[14];
    const float* W_n1   = (const float*)d_in[15];
    const float* b_n1   = (const float*)d_in[16];
    const float* W_n2   = (const float*)d_in[17];
    const float* b_n2   = (const float*)d_in[18];
    const float* ln_g   = (const float*)d_in[19];
    const float* ln_b   = (const float*)d_in[20];

    float* wsf  = (float*)d_ws;
    float* ca   = wsf;                    // 160000
    float* deg  = ca + 160000;            // 10000
    float* xacc = deg + 10000;            // 120000
    float* xbuf = xacc + 120000;          // 120000
    int* ip     = (int*)(xbuf + 120000);
    int* hist   = ip;                     // 70000
    int* pscan  = hist + 70000;           // 70000
    int* cursor = pscan + 70000;          // 70000
    int* segst  = cursor + 70000;         // 70001
    int* bsum   = segst + 70001;          // 280
    int* bofs   = bsum + 280;             // 280
    int* perm   = bofs + 280;             // 160000
    ushort_t* up = (ushort_t*)(((uintptr_t)(perm + 160000) + 15) & ~(uintptr_t)15);
    ushort_t* hb16  = up;                 // 2,560,000
    ushort_t* cab16 = hb16 + 2560000;     // 160,000
    ushort_t* mb16  = cab16 + 160000;     // 40,960,000
    ushort_t* pe1   = mb16 + 40960000;    // 2 x 147456
    ushort_t* pe2   = pe1 + 294912;       // 2 x 65536
    ushort_t* pc1   = pe2 + 131072;       // 2 x 65536
    ushort_t* pc2   = pc1 + 131072;       // 2 x 4096
    ushort_t* pn1   = pc2 + 8192;         // 2 x 524288
    ushort_t* pn2   = pn1 + 1048576;      // 2 x 65536

    hipMemsetAsync(deg, 0, (size_t)NN * sizeof(float), stream);
    hipMemsetAsync(hist, 0, (size_t)NSEG * sizeof(int), stream);
    hipMemsetAsync(cursor, 0, (size_t)NSEG * sizeof(int), stream);

    ca_kernel<<<(NN * CF + 255) / 256, 256, 0, stream>>>(cattr, cwts, ca);
    deg_kernel<<<(EE + 255) / 256, 256, 0, stream>>>(elist, deg);
    cvt_kernel<<<(NN * HH + 255) / 256, 256, 0, stream>>>(input, hb16, NN * HH);
    cvt_kernel<<<(NN * CF + 255) / 256, 256, 0, stream>>>(ca, cab16, NN * CF);

    // counting sort by seg
    hist_kernel<<<(EE + 255) / 256, 256, 0, stream>>>(elist, hist);
    scan1_kernel<<<SCB, 256, 0, stream>>>(hist, pscan, bsum);
    scan2_kernel<<<1, 64, 0, stream>>>(bsum, bofs);
    scan3_kernel<<<SCB, 256, 0, stream>>>(pscan, bofs, segst);
    scatter_kernel<<<(EE + 255) / 256, 256, 0, stream>>>(elist, segst, cursor, perm);

    for (int l = 0; l < 2; ++l) {
        pack_kernel<<<dim3(18, 16), 64, 0, stream>>>(W_e1 + (size_t)l * 560 * 256, pe1 + (size_t)l * 147456, 560, 256);
        pack_kernel<<<dim3(8, 16), 64, 0, stream>>>(W_e2 + (size_t)l * 65536, pe2 + (size_t)l * 65536, 256, 256);
        pack_kernel<<<dim3(8, 16), 64, 0, stream>>>(W_c1 + (size_t)l * 65536, pc1 + (size_t)l * 65536, 256, 256);
        pack_kernel<<<dim3(8, 1),  64, 0, stream>>>(W_c2 + (size_t)l * 4096,  pc2 + (size_t)l * 4096,  256, 16);
        pack_kernel<<<dim3(64, 16), 64, 0, stream>>>(W_n1 + (size_t)l * 524288, pn1 + (size_t)l * 524288, 2048, 256);
        pack_kernel<<<dim3(8, 16), 64, 0, stream>>>(W_n2 + (size_t)l * 65536, pn2 + (size_t)l * 65536, 256, 256);
    }

    for (int l = 0; l < 2; ++l) {
        const float* x_in = (l == 0) ? coords : xbuf;
        float* h_out = (float*)d_out;     // layer0 fp32 h never read; overwritten by layer1
        float* x_out = (l == 0) ? xbuf : ((float*)d_out + (size_t)NN * HH);

        hipMemsetAsync(xacc, 0, (size_t)NN * 12 * sizeof(float), stream);

        edge_kernel<<<EE / 32, 256, 0, stream>>>(
            elist, perm, cwts, ewts, x_in, hb16, cab16,
            W_rad + l * 256, b_rad + l * 16,
            pe1 + (size_t)l * 147456, b_e1 + l * HH,
            pe2 + (size_t)l * 65536,  b_e2 + l * HH,
            pc1 + (size_t)l * 65536,  b_c1 + l * HH,
            pc2 + (size_t)l * 4096,
            mb16, xacc);

        node_kernel<<<NN / 16, 256, 0, stream>>>(
            mb16, segst,
            pn1 + (size_t)l * 524288, b_n1 + l * HH,
            pn2 + (size_t)l * 65536,  b_n2 + l * HH,
            ln_g + l * HH, ln_b + l * HH,
            h_out, hb16);

        xout_kernel<<<(NN * 12 + 255) / 256, 256, 0, stream>>>(
            x_in, xacc, deg, x_out);
    }
}